// Round 6
// baseline (1227.147 us; speedup 1.0000x reference)
//
#include <hip/hip_runtime.h>

// ============================================================================
// CNN3_P r6:
//  - front: conv2/conv3 split into two L-halves sharing a 32KB h2 buffer ->
//    dyn LDS 64,768B -> 2 blocks/CU (was 1). Per-conv GM/GN tuned: conv3
//    GM8/GN1, conv2 GM4/GN2, conv1 GM4/GN2.
//  - fc1: M padded to 448 (28 mt), wave = 7mt x 4nt (GM4/GN2) -> 11 LDS reads
//    per 28 MFMA per kstep; chunkN=2048, S=16 XCD-pinned K-slices.
//  - prep_wf1 5-way split per row; Wp[:,:,0] pre-transposed (wp0r).
// ============================================================================

typedef __attribute__((ext_vector_type(8))) short bf16x8;
typedef __attribute__((ext_vector_type(4))) float f32x4;
typedef __attribute__((ext_vector_type(8))) unsigned short u16x8;
typedef __attribute__((ext_vector_type(4))) unsigned short u16x4;

#define DEVINL __device__ __forceinline__

DEVINL unsigned short f2bf(float f) {
  unsigned u = __builtin_bit_cast(unsigned, f);
  return (unsigned short)((u + 0x7fffu + ((u >> 16) & 1u)) >> 16);  // RNE
}
DEVINL float bf2f(unsigned short h) {
  return __builtin_bit_cast(float, ((unsigned)h) << 16);
}
DEVINL f32x4 mfma16(bf16x8 a, bf16x8 b, f32x4 c) {
  return __builtin_amdgcn_mfma_f32_16x16x32_bf16(a, b, c, 0, 0, 0);
}
DEVINL float relu(float v) { return v > 0.f ? v : 0.f; }
// swizzled LDS index (u16 units): row r, col c, row-stride 2^sh u16
DEVINL int sxg(int r, int c, int sh) {
  return (r << sh) + (((c >> 3) ^ (r & 7)) << 3) + (c & 7);
}

constexpr int NB = 4096;

// ---------------------------------------------------------------- prep weights
__global__ __launch_bounds__(256) void k_prep_w(
    const float* __restrict__ Wp, const float* __restrict__ W1,
    const float* __restrict__ W2, const float* __restrict__ W3,
    unsigned short* __restrict__ wp1r, unsigned short* __restrict__ wp0r,
    unsigned short* __restrict__ w1p, unsigned short* __restrict__ w2p,
    unsigned short* __restrict__ w3p) {
  int idx = blockIdx.x * 256 + threadIdx.x;
  if (idx < 4096) {
    int p = idx >> 6, i = idx & 63;
    wp1r[p * 64 + i] = f2bf(Wp[(p * 64 + i) * 2 + 1]);
    wp0r[i * 64 + p] = f2bf(Wp[(p * 64 + i) * 2 + 0]);
    return;
  }
  idx -= 4096;
  if (idx < 24576) {  // w1: KS=2, MT=8
    int f = idx >> 9, l = (idx >> 3) & 63, e = idx & 7;
    int mt = f & 7, t = f >> 3, ks = t & 1, k = t >> 1;
    int o = mt * 16 + (l & 15), c = ks * 32 + (l >> 4) * 8 + e;
    w1p[idx] = f2bf(W1[(o * 64 + c) * 3 + k]);
    return;
  }
  idx -= 24576;
  if (idx < 98304) {  // w2: KS=4, MT=16
    int f = idx >> 9, l = (idx >> 3) & 63, e = idx & 7;
    int mt = f & 15, t = f >> 4, ks = t & 3, k = t >> 2;
    int o = mt * 16 + (l & 15), c = ks * 32 + (l >> 4) * 8 + e;
    w2p[idx] = f2bf(W2[(o * 128 + c) * 3 + k]);
    return;
  }
  idx -= 98304;
  if (idx < 196608) {  // w3: KS=8, MT=16
    int f = idx >> 9, l = (idx >> 3) & 63, e = idx & 7;
    int mt = f & 15, t = f >> 4, ks = t & 7, k = t >> 3;
    int o = mt * 16 + (l & 15), c = ks * 32 + (l >> 4) * 8 + e;
    w3p[idx] = f2bf(W3[(o * 256 + c) * 3 + k]);
  }
}

// ---------------------------------------------------------------- Wf1 remap
// grid 448*5: m = bid/5, q = bid%5. q<4: h3-part o-range [q*64,q*64+64);
// q==4: x-part. Rows 400..447 zero-padded.
__global__ __launch_bounds__(256) void k_prep_wf1(const float* __restrict__ wf1,
                                                  unsigned short* __restrict__ wf1r) {
  extern __shared__ unsigned short tls[];  // 8448 u16
  const int m = blockIdx.x / 5, q = blockIdx.x % 5, tid = threadIdx.x;
  unsigned short* dst = wf1r + (size_t)m * 39168;
  if (m >= 400) {
    if (q < 4) {
      for (int idx = tid; idx < 7744; idx += 256) dst[q * 7744 + idx] = 0;
    } else {
      for (int idx = tid; idx < 8192; idx += 256) dst[30976 + idx] = 0;
    }
    return;
  }
  if (q < 4) {
    const float* src = wf1 + (size_t)m * 39168 + q * 7744;
    for (int idx = tid; idx < 7744; idx += 256) {
      int o = idx / 121, l = idx - o * 121;
      tls[o * 132 + l] = f2bf(src[idx]);
    }
    __syncthreads();
    for (int idx = tid; idx < 7744; idx += 256) {
      int l = idx >> 6, o = idx & 63;
      dst[l * 256 + q * 64 + o] = tls[o * 132 + l];
    }
  } else {
    const float* src = wf1 + (size_t)m * 39168 + 30976;
    for (int idx = tid; idx < 8192; idx += 256) {
      int il = idx >> 7, cl = idx & 127;
      tls[cl * 66 + il] = f2bf(src[idx]);
    }
    __syncthreads();
    for (int idx = tid; idx < 8192; idx += 256) {
      int cl = idx >> 6, il = idx & 63;
      dst[30976 + idx] = tls[cl * 66 + il];
    }
  }
}

// ---------------------------------------------------------------- conv phase
// wave-grid GM x GN; wave = MPW m-tiles x NPW n-tiles. A coalesced 1KB frags
// from packed global; B from swizzled LDS. B row = rowoff + l_local + k,
// clamped; out at l_local < outvalid (LDS local or global at outbase+l_local).
template <int CIN, int COUT, int SSHI, int SSHO, int MPW, int NPW, bool TOGLB>
DEVINL void conv_phase(const unsigned short* in_lds,
                       const unsigned short* __restrict__ wpack,
                       const float* __restrict__ bias,
                       unsigned short* out_lds, unsigned short* h3, int b,
                       int lane, int wv, int rowoff, int rowclamp, int outbase,
                       int outvalid) {
  constexpr int KS = CIN / 32;
  constexpr int MT = COUT / 16;
  constexpr int GM = MT / MPW;
  constexpr int GN = 8 / GM;
  static_assert(GM * GN == 8, "");
  const int lr = lane & 15, lq = lane >> 4;
  const int wm = wv / GN, wn = wv % GN;
  f32x4 acc[MPW][NPW];
#pragma unroll
  for (int mi = 0; mi < MPW; ++mi)
#pragma unroll
    for (int ni = 0; ni < NPW; ++ni) acc[mi][ni] = (f32x4){0.f, 0.f, 0.f, 0.f};
#pragma unroll
  for (int k = 0; k < 3; ++k)
#pragma unroll
    for (int ks = 0; ks < KS; ++ks) {
      bf16x8 a[MPW];
#pragma unroll
      for (int mi = 0; mi < MPW; ++mi)
        a[mi] = *(const bf16x8*)(wpack +
                                 (((k * KS + ks) * MT + wm * MPW + mi) << 9) +
                                 lane * 8);
      const int col = ks * 32 + lq * 8;
#pragma unroll
      for (int ni = 0; ni < NPW; ++ni) {
        int row = rowoff + (wn * NPW + ni) * 16 + lr + k;
        if (row > rowclamp) row = rowclamp;
        bf16x8 bb = *(const bf16x8*)(in_lds + sxg(row, col, SSHI));
#pragma unroll
        for (int mi = 0; mi < MPW; ++mi)
          acc[mi][ni] = mfma16(a[mi], bb, acc[mi][ni]);
      }
    }
#pragma unroll
  for (int mi = 0; mi < MPW; ++mi) {
    const int o0 = (wm * MPW + mi) * 16 + lq * 4;
    const f32x4 bi = *(const f32x4*)(bias + o0);
#pragma unroll
    for (int ni = 0; ni < NPW; ++ni) {
      const int ll = (wn * NPW + ni) * 16 + lr;
      if (ll < outvalid) {
        u16x4 pk;
#pragma unroll
        for (int r = 0; r < 4; ++r) pk[r] = f2bf(relu(acc[mi][ni][r] + bi[r]));
        if constexpr (TOGLB)
          *(u16x4*)(h3 + ((size_t)b * 121 + outbase + ll) * 256 + o0) = pk;
        else
          *(u16x4*)(out_lds + sxg(ll, o0, SSHO)) = pk;
      }
    }
  }
}

// ---------------------------------------------------------------- fused front
// LDS (u16): xs @0 (128<<6=8192), h0s @8192 (127<<6=8128),
//            h2h @0 (64<<8=16384, aliases xs+h0s after conv1),
//            h1s @16384 (125<<7=16000).  dyn = 64,768 B -> 2 blocks/CU.
__global__ __launch_bounds__(512, 4) void k_front(
    const float* __restrict__ x, const unsigned short* __restrict__ wp0r,
    const float* __restrict__ bp, const unsigned short* __restrict__ wp1r,
    const unsigned short* __restrict__ w1p, const float* __restrict__ b1,
    const unsigned short* __restrict__ w2p, const float* __restrict__ b2,
    const unsigned short* __restrict__ w3p, const float* __restrict__ b3,
    unsigned short* __restrict__ h3) {
  extern __shared__ unsigned short lds[];
  unsigned short* xs = lds;
  unsigned short* h0s = lds + 8192;
  unsigned short* h2h = lds;
  unsigned short* h1s = lds + 16384;
  __shared__ float pbase[8][64];
  __shared__ float basel[64];
  const int b = blockIdx.x, tid = threadIdx.x;
  const int lane = tid & 63, wv = tid >> 6, lq = lane >> 4, lr = lane & 15;
  const float* xb = x + (size_t)b * 8192;

  // phase 0: stage x -> xs bf16 [cl][il] swizzled
  for (int idx = tid * 4; idx < 8192; idx += 2048) {
    f32x4 v = *(const f32x4*)(xb + idx);
    int c = idx >> 6, i = idx & 63;
    u16x4 pk;
#pragma unroll
    for (int r = 0; r < 4; ++r) pk[r] = f2bf(v[r]);
    *(u16x4*)(xs + sxg(c, i, 6)) = pk;
  }
  __syncthreads();

  // phase 0b: base[p] = sum_i Wp0[i][p]*x[b][i]  (xs row 0 unswizzled)
  {
    int p = tid & 63, q = tid >> 6;
    float s = 0.f;
#pragma unroll
    for (int t = 0; t < 8; ++t) {
      int i = q * 8 + t;
      s += bf2f(wp0r[i * 64 + p]) * bf2f(xs[i]);
    }
    pbase[q][p] = s;
  }
  __syncthreads();
  if (tid < 64) {
    float s = bp[tid];
#pragma unroll
    for (int q = 0; q < 8; ++q) s += pbase[q][tid];
    basel[tid] = s;
  }
  __syncthreads();

  // phase 1: pairwise GEMM -> h0s[127][64]
  {
    const int mt = wv & 3, nh = wv >> 2;
    f32x4 acc[4];
#pragma unroll
    for (int t = 0; t < 4; ++t) acc[t] = (f32x4){0.f, 0.f, 0.f, 0.f};
#pragma unroll
    for (int s = 0; s < 2; ++s) {
      bf16x8 a = *(const bf16x8*)(wp1r + (mt * 16 + lr) * 64 + s * 32 + lq * 8);
#pragma unroll
      for (int t = 0; t < 4; ++t) {
        int j = (nh * 4 + t) * 16 + lr;
        int row = j + 1 > 127 ? 127 : j + 1;
        bf16x8 bb = *(const bf16x8*)(xs + sxg(row, s * 32 + lq * 8, 6));
        acc[t] = mfma16(a, bb, acc[t]);
      }
    }
    const int m0 = mt * 16 + lq * 4;
    f32x4 bl;
#pragma unroll
    for (int r = 0; r < 4; ++r) bl[r] = basel[m0 + r];
#pragma unroll
    for (int t = 0; t < 4; ++t) {
      int j = (nh * 4 + t) * 16 + lr;
      if (j < 127) {
        u16x4 pk;
#pragma unroll
        for (int r = 0; r < 4; ++r) pk[r] = f2bf(relu(acc[t][r] + bl[r]));
        *(u16x4*)(h0s + sxg(j, m0, 6)) = pk;
      }
    }
  }
  __syncthreads();

  // conv1 64->128, L 127->125 (GM4/GN2, MPW2/NPW4)
  conv_phase<64, 128, 6, 7, 2, 4, false>(h0s, w1p, b1, h1s, nullptr, b, lane,
                                         wv, 0, 126, 0, 125);
  __syncthreads();
  // conv2 half1: h1[0..65] -> h2h[0..63] (GM4/GN2, MPW4/NPW2)
  conv_phase<128, 256, 7, 8, 4, 2, false>(h1s, w2p, b2, h2h, nullptr, b, lane,
                                          wv, 0, 124, 0, 64);
  __syncthreads();
  // conv3 half1: h2h[0..63] -> out l 0..61 (GM8/GN1, MPW2/NPW4)
  conv_phase<256, 256, 8, 0, 2, 4, true>(h2h, w3p, b3, nullptr, h3, b, lane,
                                         wv, 0, 63, 0, 62);
  __syncthreads();
  // conv2 half2: h1[62..124] -> h2h[0..60]
  conv_phase<128, 256, 7, 8, 4, 2, false>(h1s, w2p, b2, h2h, nullptr, b, lane,
                                          wv, 62, 124, 0, 61);
  __syncthreads();
  // conv3 half2: h2h[0..60] -> out l 62..120
  conv_phase<256, 256, 8, 0, 2, 4, true>(h2h, w3p, b3, nullptr, h3, b, lane,
                                         wv, 0, 63, 62, 59);
}

// ---------------------------------------------------------------- fc1
// M=448 (28 mt, rows 400..447 zero), block 448m x 128n, S K-slices
// (slice = bid%S -> slice%8 = XCD pin). Wave = 7mt x 4nt (GM4/GN2).
__global__ __launch_bounds__(512, 2) void k_fc1(
    const unsigned short* __restrict__ h3, const float* __restrict__ x,
    const unsigned short* __restrict__ wf1r, float* __restrict__ fpart,
    int chunkN, int S) {
  __shared__ unsigned short lA[448 * 40];  // 35,840 B
  __shared__ unsigned short lB[128 * 40];  // 10,240 B
  const int tid = threadIdx.x;
  const int lane = tid & 63, wv = tid >> 6, lq = lane >> 4, lr = lane & 15;
  const int slice = blockIdx.x % S;
  const int bbase = (blockIdx.x / S) * 128;
  const int per = 1224 / S, rem = 1224 % S;
  const int c0 = slice * per + (slice < rem ? slice : rem);
  const int c1 = c0 + per + (slice < rem ? 1 : 0);
  const int mgrp = wv >> 1, ngrp = wv & 1;

  f32x4 acc[7][4];
#pragma unroll
  for (int mt = 0; mt < 7; ++mt)
#pragma unroll
    for (int ni = 0; ni < 4; ++ni) acc[mt][ni] = (f32x4){0.f, 0.f, 0.f, 0.f};

  for (int kc = c0; kc < c1; ++kc) {
    const int k0 = kc * 32;
    // stage A: 448 rows x 4 x 16B chunks
#pragma unroll
    for (int t = 0; t < 4; ++t) {
      int idx = tid + t * 512;
      if (idx < 1792) {
        int m = idx >> 2, ch = idx & 3;
        *(u16x8*)(lA + m * 40 + ch * 8) =
            *(const u16x8*)(wf1r + (size_t)m * 39168 + k0 + ch * 8);
      }
    }
    // stage B: 128 rows x 4 chunks (one per thread)
    {
      int n = tid >> 2, ch = tid & 3;
      int bb = bbase + n;
      u16x8 v;
      if (k0 < 30976) {  // 30976 % 32 == 0: per-kc branch handles straddle
        v = *(const u16x8*)(h3 + (size_t)bb * 30976 + k0 + ch * 8);
      } else {
        const float* sxp = x + (size_t)bb * 8192 + (k0 - 30976) + ch * 8;
        f32x4 v0 = *(const f32x4*)sxp;
        f32x4 v1 = *(const f32x4*)(sxp + 4);
#pragma unroll
        for (int r = 0; r < 4; ++r) {
          v[r] = f2bf(v0[r]);
          v[4 + r] = f2bf(v1[r]);
        }
      }
      *(u16x8*)(lB + n * 40 + ch * 8) = v;
    }
    __syncthreads();
    bf16x8 bfr[4];
#pragma unroll
    for (int ni = 0; ni < 4; ++ni)
      bfr[ni] = *(const bf16x8*)(lB + (ngrp * 64 + ni * 16 + lr) * 40 + lq * 8);
#pragma unroll
    for (int mt = 0; mt < 7; ++mt) {
      bf16x8 afr =
          *(const bf16x8*)(lA + (mgrp * 112 + mt * 16 + lr) * 40 + lq * 8);
#pragma unroll
      for (int ni = 0; ni < 4; ++ni)
        acc[mt][ni] = mfma16(afr, bfr[ni], acc[mt][ni]);
    }
    __syncthreads();
  }

#pragma unroll
  for (int mt = 0; mt < 7; ++mt) {
    const int m0 = mgrp * 112 + mt * 16 + lq * 4;
#pragma unroll
    for (int ni = 0; ni < 4; ++ni) {
      const int bb = bbase + ngrp * 64 + ni * 16 + lr;
      *(f32x4*)(fpart + ((size_t)slice * chunkN + bb) * 448 + m0) = acc[mt][ni];
    }
  }
}

__global__ __launch_bounds__(256) void k_fc1red(const float* __restrict__ fpart,
                                                const float* __restrict__ bf1,
                                                float* __restrict__ fc,
                                                int chunkN, int S) {
  int idx = blockIdx.x * 256 + threadIdx.x;
  if (idx >= chunkN * 400) return;
  int bq = idx / 400, m = idx - bq * 400;
  float s = bf1[m];
  for (int sl = 0; sl < S; ++sl)
    s += fpart[((size_t)sl * chunkN + bq) * 448 + m];
  fc[idx] = relu(s);
}

__global__ __launch_bounds__(256) void k_fc2(const float* __restrict__ fc,
                                             const float* __restrict__ wf2,
                                             const float* __restrict__ bf2,
                                             float* __restrict__ out) {
  int b = blockIdx.x * 4 + (threadIdx.x >> 6);
  int lane = threadIdx.x & 63;
  float s = 0.f;
  for (int m = lane; m < 400; m += 64) s += fc[(size_t)b * 400 + m] * wf2[m];
#pragma unroll
  for (int off = 32; off > 0; off >>= 1) s += __shfl_down(s, off, 64);
  if (lane == 0) out[b] = s + bf2[0];
}

// ---------------------------------------------------------------- launch
extern "C" void kernel_launch(void* const* d_in, const int* in_sizes, int n_in,
                              void* d_out, int out_size, void* d_ws, size_t ws_size,
                              hipStream_t stream) {
  const float* x = (const float*)d_in[0];
  const float* Wp = (const float*)d_in[1];
  const float* bp = (const float*)d_in[2];
  const float* W1 = (const float*)d_in[3];
  const float* b1 = (const float*)d_in[4];
  const float* W2 = (const float*)d_in[5];
  const float* b2 = (const float*)d_in[6];
  const float* W3 = (const float*)d_in[7];
  const float* b3 = (const float*)d_in[8];
  const float* Wf1 = (const float*)d_in[9];
  const float* bf1 = (const float*)d_in[10];
  const float* Wf2 = (const float*)d_in[11];
  const float* bf2 = (const float*)d_in[12];
  float* out = (float*)d_out;

  // fixed: wp1r 8K + wp0r 8K + w1p 48K + w2p 192K + w3p 384K + wf1r 448x39168x2
  const size_t fixed = 8192 + 8192 + 49152 + 196608 + 393216 + 448ULL * 39168 * 2;
  static const int cand[4][2] = {{2048, 16}, {1024, 32}, {512, 64}, {512, 32}};
  int chunkN = 512, S = 32;
  for (int i = 0; i < 4; ++i) {
    size_t cn = cand[i][0], s = cand[i][1];
    size_t need = fixed + cn * (61952ULL + 1600ULL) + s * cn * 1792ULL;
    if (need <= ws_size) {
      chunkN = cand[i][0];
      S = cand[i][1];
      break;
    }
  }
  const int nchunk = NB / chunkN;

  char* ws = (char*)d_ws;
  size_t off = 0;
  unsigned short* h3c = (unsigned short*)(ws + off);
  off += (size_t)chunkN * 61952ULL;
  float* fpart = (float*)(ws + off);
  off += (size_t)S * chunkN * 1792ULL;
  float* fc = (float*)(ws + off);
  off += (size_t)chunkN * 1600ULL;
  unsigned short* wp1r = (unsigned short*)(ws + off);
  off += 8192;
  unsigned short* wp0r = (unsigned short*)(ws + off);
  off += 8192;
  unsigned short* w1p = (unsigned short*)(ws + off);
  off += 49152;
  unsigned short* w2p = (unsigned short*)(ws + off);
  off += 196608;
  unsigned short* w3p = (unsigned short*)(ws + off);
  off += 393216;
  unsigned short* wf1r = (unsigned short*)(ws + off);

  k_prep_w<<<1264, 256, 0, stream>>>(Wp, W1, W2, W3, wp1r, wp0r, w1p, w2p, w3p);
  k_prep_wf1<<<448 * 5, 256, 16896, stream>>>(Wf1, wf1r);

  for (int c = 0; c < nchunk; ++c) {
    const float* xc = x + (size_t)c * chunkN * 8192;
    k_front<<<chunkN, 512, 64768, stream>>>(xc, wp0r, bp, wp1r, w1p, b1, w2p,
                                            b2, w3p, b3, h3c);
    k_fc1<<<(chunkN / 128) * S, 512, 0, stream>>>(h3c, xc, wf1r, fpart, chunkN, S);
    k_fc1red<<<(chunkN * 400 + 255) / 256, 256, 0, stream>>>(fpart, bf1, fc,
                                                             chunkN, S);
    k_fc2<<<chunkN / 4, 256, 0, stream>>>(fc, Wf2, bf2, out + (size_t)c * chunkN);
  }
}

// Round 7
// 781.051 us; speedup vs baseline: 1.5711x; 1.5711x over previous
//
#include <hip/hip_runtime.h>

// ============================================================================
// CNN3_P r7 = r4-best + r6's front structure minus the spill bug:
//  - front: conv2/conv3 split into two L-halves sharing a 32KB h2 buffer ->
//    dyn LDS 64,768B -> 2 blocks/CU NATURALLY (plain __launch_bounds__(512);
//    r6's ",4" forced VGPR=64 -> spills -> 1GB scratch traffic/dispatch).
//  - fc1: r4's verified version (S=32 XCD-pinned 0.97MB panels, A-frags from
//    L2, lB swizzled).
//  - prep_wf1 5-way split per row; Wp[:,:,0] pre-transposed (wp0r).
// ============================================================================

typedef __attribute__((ext_vector_type(8))) short bf16x8;
typedef __attribute__((ext_vector_type(4))) float f32x4;
typedef __attribute__((ext_vector_type(8))) unsigned short u16x8;
typedef __attribute__((ext_vector_type(4))) unsigned short u16x4;

#define DEVINL __device__ __forceinline__

DEVINL unsigned short f2bf(float f) {
  unsigned u = __builtin_bit_cast(unsigned, f);
  return (unsigned short)((u + 0x7fffu + ((u >> 16) & 1u)) >> 16);  // RNE
}
DEVINL float bf2f(unsigned short h) {
  return __builtin_bit_cast(float, ((unsigned)h) << 16);
}
DEVINL f32x4 mfma16(bf16x8 a, bf16x8 b, f32x4 c) {
  return __builtin_amdgcn_mfma_f32_16x16x32_bf16(a, b, c, 0, 0, 0);
}
DEVINL float relu(float v) { return v > 0.f ? v : 0.f; }
// swizzled LDS index (u16 units): row r, col c, row-stride 2^sh u16
DEVINL int sxg(int r, int c, int sh) {
  return (r << sh) + (((c >> 3) ^ (r & 7)) << 3) + (c & 7);
}

constexpr int NB = 4096;

// ---------------------------------------------------------------- prep weights
__global__ __launch_bounds__(256) void k_prep_w(
    const float* __restrict__ Wp, const float* __restrict__ W1,
    const float* __restrict__ W2, const float* __restrict__ W3,
    unsigned short* __restrict__ wp1r, unsigned short* __restrict__ wp0r,
    unsigned short* __restrict__ w1p, unsigned short* __restrict__ w2p,
    unsigned short* __restrict__ w3p) {
  int idx = blockIdx.x * 256 + threadIdx.x;
  if (idx < 4096) {
    int p = idx >> 6, i = idx & 63;
    wp1r[p * 64 + i] = f2bf(Wp[(p * 64 + i) * 2 + 1]);
    wp0r[i * 64 + p] = f2bf(Wp[(p * 64 + i) * 2 + 0]);
    return;
  }
  idx -= 4096;
  if (idx < 24576) {  // w1: KS=2, MT=8
    int f = idx >> 9, l = (idx >> 3) & 63, e = idx & 7;
    int mt = f & 7, t = f >> 3, ks = t & 1, k = t >> 1;
    int o = mt * 16 + (l & 15), c = ks * 32 + (l >> 4) * 8 + e;
    w1p[idx] = f2bf(W1[(o * 64 + c) * 3 + k]);
    return;
  }
  idx -= 24576;
  if (idx < 98304) {  // w2: KS=4, MT=16
    int f = idx >> 9, l = (idx >> 3) & 63, e = idx & 7;
    int mt = f & 15, t = f >> 4, ks = t & 3, k = t >> 2;
    int o = mt * 16 + (l & 15), c = ks * 32 + (l >> 4) * 8 + e;
    w2p[idx] = f2bf(W2[(o * 128 + c) * 3 + k]);
    return;
  }
  idx -= 98304;
  if (idx < 196608) {  // w3: KS=8, MT=16
    int f = idx >> 9, l = (idx >> 3) & 63, e = idx & 7;
    int mt = f & 15, t = f >> 4, ks = t & 7, k = t >> 3;
    int o = mt * 16 + (l & 15), c = ks * 32 + (l >> 4) * 8 + e;
    w3p[idx] = f2bf(W3[(o * 256 + c) * 3 + k]);
  }
}

// ---------------------------------------------------------------- Wf1 remap
// grid 400*5: m = bid/5, q = bid%5. q<4: h3-part o-range [q*64,(q+1)*64);
// q==4: x-part.
__global__ __launch_bounds__(256) void k_prep_wf1(const float* __restrict__ wf1,
                                                  unsigned short* __restrict__ wf1r) {
  extern __shared__ unsigned short tls[];  // 8448 u16
  const int m = blockIdx.x / 5, q = blockIdx.x % 5, tid = threadIdx.x;
  unsigned short* dst = wf1r + (size_t)m * 39168;
  if (q < 4) {
    const float* src = wf1 + (size_t)m * 39168 + q * 7744;
    for (int idx = tid; idx < 7744; idx += 256) {
      int o = idx / 121, l = idx - o * 121;
      tls[o * 132 + l] = f2bf(src[idx]);
    }
    __syncthreads();
    for (int idx = tid; idx < 7744; idx += 256) {
      int l = idx >> 6, o = idx & 63;
      dst[l * 256 + q * 64 + o] = tls[o * 132 + l];
    }
  } else {
    const float* src = wf1 + (size_t)m * 39168 + 30976;
    for (int idx = tid; idx < 8192; idx += 256) {
      int il = idx >> 7, cl = idx & 127;
      tls[cl * 66 + il] = f2bf(src[idx]);
    }
    __syncthreads();
    for (int idx = tid; idx < 8192; idx += 256) {
      int cl = idx >> 6, il = idx & 63;
      dst[30976 + idx] = tls[cl * 66 + il];
    }
  }
}

// ---------------------------------------------------------------- conv phase
// wave-grid GM x GN; wave = MPW m-tiles x NPW n-tiles. A coalesced 1KB frags
// from packed global; B from swizzled LDS. B row = rowoff + l_local + k,
// clamped; out at l_local < outvalid.
template <int CIN, int COUT, int SSHI, int SSHO, int MPW, int NPW, bool TOGLB>
DEVINL void conv_phase(const unsigned short* in_lds,
                       const unsigned short* __restrict__ wpack,
                       const float* __restrict__ bias,
                       unsigned short* out_lds, unsigned short* h3, int b,
                       int lane, int wv, int rowoff, int rowclamp, int outbase,
                       int outvalid) {
  constexpr int KS = CIN / 32;
  constexpr int MT = COUT / 16;
  constexpr int GM = MT / MPW;
  constexpr int GN = 8 / GM;
  static_assert(GM * GN == 8, "");
  const int lr = lane & 15, lq = lane >> 4;
  const int wm = wv / GN, wn = wv % GN;
  f32x4 acc[MPW][NPW];
#pragma unroll
  for (int mi = 0; mi < MPW; ++mi)
#pragma unroll
    for (int ni = 0; ni < NPW; ++ni) acc[mi][ni] = (f32x4){0.f, 0.f, 0.f, 0.f};
#pragma unroll
  for (int k = 0; k < 3; ++k)
#pragma unroll
    for (int ks = 0; ks < KS; ++ks) {
      bf16x8 a[MPW];
#pragma unroll
      for (int mi = 0; mi < MPW; ++mi)
        a[mi] = *(const bf16x8*)(wpack +
                                 (((k * KS + ks) * MT + wm * MPW + mi) << 9) +
                                 lane * 8);
      const int col = ks * 32 + lq * 8;
#pragma unroll
      for (int ni = 0; ni < NPW; ++ni) {
        int row = rowoff + (wn * NPW + ni) * 16 + lr + k;
        if (row > rowclamp) row = rowclamp;
        bf16x8 bb = *(const bf16x8*)(in_lds + sxg(row, col, SSHI));
#pragma unroll
        for (int mi = 0; mi < MPW; ++mi)
          acc[mi][ni] = mfma16(a[mi], bb, acc[mi][ni]);
      }
    }
#pragma unroll
  for (int mi = 0; mi < MPW; ++mi) {
    const int o0 = (wm * MPW + mi) * 16 + lq * 4;
    const f32x4 bi = *(const f32x4*)(bias + o0);
#pragma unroll
    for (int ni = 0; ni < NPW; ++ni) {
      const int ll = (wn * NPW + ni) * 16 + lr;
      if (ll < outvalid) {
        u16x4 pk;
#pragma unroll
        for (int r = 0; r < 4; ++r) pk[r] = f2bf(relu(acc[mi][ni][r] + bi[r]));
        if constexpr (TOGLB)
          *(u16x4*)(h3 + ((size_t)b * 121 + outbase + ll) * 256 + o0) = pk;
        else
          *(u16x4*)(out_lds + sxg(ll, o0, SSHO)) = pk;
      }
    }
  }
}

// ---------------------------------------------------------------- fused front
// LDS (u16): xs @0 (128<<6=8192), h0s @8192 (127<<6=8128),
//            h2h @0 (64<<8=16384, aliases xs+h0s after conv1),
//            h1s @16384 (125<<7=16000).  dyn = 64,768 B -> 2 blocks/CU.
// NOTE: plain __launch_bounds__(512) — r6's ",4" caused VGPR=64 + spills.
__global__ __launch_bounds__(512) void k_front(
    const float* __restrict__ x, const unsigned short* __restrict__ wp0r,
    const float* __restrict__ bp, const unsigned short* __restrict__ wp1r,
    const unsigned short* __restrict__ w1p, const float* __restrict__ b1,
    const unsigned short* __restrict__ w2p, const float* __restrict__ b2,
    const unsigned short* __restrict__ w3p, const float* __restrict__ b3,
    unsigned short* __restrict__ h3) {
  extern __shared__ unsigned short lds[];
  unsigned short* xs = lds;
  unsigned short* h0s = lds + 8192;
  unsigned short* h2h = lds;
  unsigned short* h1s = lds + 16384;
  __shared__ float pbase[8][64];
  __shared__ float basel[64];
  const int b = blockIdx.x, tid = threadIdx.x;
  const int lane = tid & 63, wv = tid >> 6, lq = lane >> 4, lr = lane & 15;
  const float* xb = x + (size_t)b * 8192;

  // phase 0: stage x -> xs bf16 [cl][il] swizzled
  for (int idx = tid * 4; idx < 8192; idx += 2048) {
    f32x4 v = *(const f32x4*)(xb + idx);
    int c = idx >> 6, i = idx & 63;
    u16x4 pk;
#pragma unroll
    for (int r = 0; r < 4; ++r) pk[r] = f2bf(v[r]);
    *(u16x4*)(xs + sxg(c, i, 6)) = pk;
  }
  __syncthreads();

  // phase 0b: base[p] = sum_i Wp0[i][p]*x[b][i]  (xs row 0 unswizzled)
  {
    int p = tid & 63, q = tid >> 6;
    float s = 0.f;
#pragma unroll
    for (int t = 0; t < 8; ++t) {
      int i = q * 8 + t;
      s += bf2f(wp0r[i * 64 + p]) * bf2f(xs[i]);
    }
    pbase[q][p] = s;
  }
  __syncthreads();
  if (tid < 64) {
    float s = bp[tid];
#pragma unroll
    for (int q = 0; q < 8; ++q) s += pbase[q][tid];
    basel[tid] = s;
  }
  __syncthreads();

  // phase 1: pairwise GEMM -> h0s[127][64]
  {
    const int mt = wv & 3, nh = wv >> 2;
    f32x4 acc[4];
#pragma unroll
    for (int t = 0; t < 4; ++t) acc[t] = (f32x4){0.f, 0.f, 0.f, 0.f};
#pragma unroll
    for (int s = 0; s < 2; ++s) {
      bf16x8 a = *(const bf16x8*)(wp1r + (mt * 16 + lr) * 64 + s * 32 + lq * 8);
#pragma unroll
      for (int t = 0; t < 4; ++t) {
        int j = (nh * 4 + t) * 16 + lr;
        int row = j + 1 > 127 ? 127 : j + 1;
        bf16x8 bb = *(const bf16x8*)(xs + sxg(row, s * 32 + lq * 8, 6));
        acc[t] = mfma16(a, bb, acc[t]);
      }
    }
    const int m0 = mt * 16 + lq * 4;
    f32x4 bl;
#pragma unroll
    for (int r = 0; r < 4; ++r) bl[r] = basel[m0 + r];
#pragma unroll
    for (int t = 0; t < 4; ++t) {
      int j = (nh * 4 + t) * 16 + lr;
      if (j < 127) {
        u16x4 pk;
#pragma unroll
        for (int r = 0; r < 4; ++r) pk[r] = f2bf(relu(acc[t][r] + bl[r]));
        *(u16x4*)(h0s + sxg(j, m0, 6)) = pk;
      }
    }
  }
  __syncthreads();

  // conv1 64->128, L 127->125 (GM4/GN2, MPW2/NPW4)
  conv_phase<64, 128, 6, 7, 2, 4, false>(h0s, w1p, b1, h1s, nullptr, b, lane,
                                         wv, 0, 126, 0, 125);
  __syncthreads();
  // conv2 half1: h1[0..65] -> h2h[0..63] (GM4/GN2, MPW4/NPW2)
  conv_phase<128, 256, 7, 8, 4, 2, false>(h1s, w2p, b2, h2h, nullptr, b, lane,
                                          wv, 0, 124, 0, 64);
  __syncthreads();
  // conv3 half1: h2h[0..63] -> out l 0..61 (GM8/GN1, MPW2/NPW4)
  conv_phase<256, 256, 8, 0, 2, 4, true>(h2h, w3p, b3, nullptr, h3, b, lane,
                                         wv, 0, 63, 0, 62);
  __syncthreads();
  // conv2 half2: h1[62..124] -> h2h[0..60]
  conv_phase<128, 256, 7, 8, 4, 2, false>(h1s, w2p, b2, h2h, nullptr, b, lane,
                                          wv, 62, 124, 0, 61);
  __syncthreads();
  // conv3 half2: h2h[0..60] -> out l 62..120
  conv_phase<256, 256, 8, 0, 2, 4, true>(h2h, w3p, b3, nullptr, h3, b, lane,
                                         wv, 0, 63, 62, 59);
}

// ---------------------------------------------------------------- fc1 (r4)
// grid (chunkN/128)*32, slice = bid&31 (slice%8 = XCD -> 4 slices/XCD, wf1r
// slice set ~3.9MB L2-resident). A-frags in regs from global; lB swizzled.
__global__ __launch_bounds__(512) void k_fc1(const unsigned short* __restrict__ h3,
                                             const float* __restrict__ x,
                                             const unsigned short* __restrict__ wf1r,
                                             float* __restrict__ fpart, int chunkN) {
  __shared__ unsigned short lB[128 * 64];
  const int tid = threadIdx.x;
  const int lane = tid & 63, wv = tid >> 6, lq = lane >> 4, lr = lane & 15;
  const int slice = blockIdx.x & 31;
  const int bbase = (blockIdx.x >> 5) * 128;
  const int c0 = slice * 19 + (slice < 4 ? slice : 4);
  const int c1 = c0 + 19 + (slice < 4 ? 1 : 0);

  f32x4 acc[3][8], acc24;
#pragma unroll
  for (int mi = 0; mi < 3; ++mi)
#pragma unroll
    for (int nt = 0; nt < 8; ++nt) acc[mi][nt] = (f32x4){0.f, 0.f, 0.f, 0.f};
  acc24 = (f32x4){0.f, 0.f, 0.f, 0.f};

  const size_t arow0 = (size_t)((3 * wv + 0) * 16 + lr) * 39168;
  const size_t arow1 = (size_t)((3 * wv + 1) * 16 + lr) * 39168;
  const size_t arow2 = (size_t)((3 * wv + 2) * 16 + lr) * 39168;
  const size_t arow24 = (size_t)(384 + lr) * 39168;

  for (int kc = c0; kc < c1; ++kc) {
    const int k0 = kc * 64;
#pragma unroll
    for (int t = 0; t < 2; ++t) {
      int idx = tid + t * 512;
      int n = idx >> 3, ch = idx & 7;
      int bb = bbase + n;
      u16x8 v;
      if (k0 < 30976) {  // 30976 % 64 == 0: never straddles
        v = *(const u16x8*)(h3 + (size_t)bb * 30976 + k0 + ch * 8);
      } else {
        const float* sxp = x + (size_t)bb * 8192 + (k0 - 30976) + ch * 8;
        f32x4 v0 = *(const f32x4*)sxp;
        f32x4 v1 = *(const f32x4*)(sxp + 4);
#pragma unroll
        for (int r = 0; r < 4; ++r) {
          v[r] = f2bf(v0[r]);
          v[4 + r] = f2bf(v1[r]);
        }
      }
      *(u16x8*)(lB + (n << 6) + ((ch ^ (n & 7)) << 3)) = v;
    }
    __syncthreads();

#pragma unroll
    for (int win = 0; win < 2; ++win) {
      const int koff = k0 + win * 32 + lq * 8;
      bf16x8 a0 = *(const bf16x8*)(wf1r + arow0 + koff);
      bf16x8 a1 = *(const bf16x8*)(wf1r + arow1 + koff);
      bf16x8 a2 = *(const bf16x8*)(wf1r + arow2 + koff);
      bf16x8 a24 = *(const bf16x8*)(wf1r + arow24 + koff);
      const int cloc = win * 32 + lq * 8;
#pragma unroll
      for (int nt = 0; nt < 8; ++nt) {
        const int n = nt * 16 + lr;
        bf16x8 bb = *(const bf16x8*)(lB + sxg(n, cloc, 6));
        acc[0][nt] = mfma16(a0, bb, acc[0][nt]);
        acc[1][nt] = mfma16(a1, bb, acc[1][nt]);
        acc[2][nt] = mfma16(a2, bb, acc[2][nt]);
      }
      {
        const int n = wv * 16 + lr;
        bf16x8 bb = *(const bf16x8*)(lB + sxg(n, cloc, 6));
        acc24 = mfma16(a24, bb, acc24);
      }
    }
    __syncthreads();
  }

#pragma unroll
  for (int mi = 0; mi < 3; ++mi) {
    const int m0 = (3 * wv + mi) * 16 + lq * 4;
#pragma unroll
    for (int nt = 0; nt < 8; ++nt) {
      const int bb = bbase + nt * 16 + lr;
      *(f32x4*)(fpart + ((size_t)slice * chunkN + bb) * 400 + m0) = acc[mi][nt];
    }
  }
  {
    const int bb = bbase + wv * 16 + lr;
    *(f32x4*)(fpart + ((size_t)slice * chunkN + bb) * 400 + 384 + lq * 4) = acc24;
  }
}

__global__ __launch_bounds__(256) void k_fc1red(const float* __restrict__ fpart,
                                                const float* __restrict__ bf1,
                                                float* __restrict__ fc, int chunkN) {
  int idx = blockIdx.x * 256 + threadIdx.x;
  if (idx >= chunkN * 400) return;
  int m = idx % 400;
  float s = bf1[m];
  size_t stride = (size_t)chunkN * 400;
#pragma unroll 8
  for (int sl = 0; sl < 32; ++sl) s += fpart[(size_t)sl * stride + idx];
  fc[idx] = relu(s);
}

__global__ __launch_bounds__(256) void k_fc2(const float* __restrict__ fc,
                                             const float* __restrict__ wf2,
                                             const float* __restrict__ bf2,
                                             float* __restrict__ out) {
  int b = blockIdx.x * 4 + (threadIdx.x >> 6);
  int lane = threadIdx.x & 63;
  float s = 0.f;
  for (int m = lane; m < 400; m += 64) s += fc[(size_t)b * 400 + m] * wf2[m];
#pragma unroll
  for (int off = 32; off > 0; off >>= 1) s += __shfl_down(s, off, 64);
  if (lane == 0) out[b] = s + bf2[0];
}

// ---------------------------------------------------------------- launch
extern "C" void kernel_launch(void* const* d_in, const int* in_sizes, int n_in,
                              void* d_out, int out_size, void* d_ws, size_t ws_size,
                              hipStream_t stream) {
  const float* x = (const float*)d_in[0];
  const float* Wp = (const float*)d_in[1];
  const float* bp = (const float*)d_in[2];
  const float* W1 = (const float*)d_in[3];
  const float* b1 = (const float*)d_in[4];
  const float* W2 = (const float*)d_in[5];
  const float* b2 = (const float*)d_in[6];
  const float* W3 = (const float*)d_in[7];
  const float* b3 = (const float*)d_in[8];
  const float* Wf1 = (const float*)d_in[9];
  const float* bf1 = (const float*)d_in[10];
  const float* Wf2 = (const float*)d_in[11];
  const float* bf2 = (const float*)d_in[12];
  float* out = (float*)d_out;

  const size_t fixed =
      8192 + 8192 + 49152 + 196608 + 393216 + 400ULL * 39168 * 2;
  static const int cand[4] = {4, 8, 16, 32};
  int nchunk = 32;
  for (int i = 0; i < 4; ++i) {
    size_t cn = NB / cand[i];
    size_t need = fixed + cn * 61952ULL + 32ULL * cn * 1600ULL + cn * 1600ULL;
    if (need <= ws_size) {
      nchunk = cand[i];
      break;
    }
  }
  const int chunkN = NB / nchunk;

  char* ws = (char*)d_ws;
  size_t off = 0;
  unsigned short* h3c = (unsigned short*)(ws + off);
  off += (size_t)chunkN * 61952ULL;
  float* fpart = (float*)(ws + off);
  off += 32ULL * chunkN * 1600ULL;
  float* fc = (float*)(ws + off);
  off += (size_t)chunkN * 1600ULL;
  unsigned short* wp1r = (unsigned short*)(ws + off);
  off += 8192;
  unsigned short* wp0r = (unsigned short*)(ws + off);
  off += 8192;
  unsigned short* w1p = (unsigned short*)(ws + off);
  off += 49152;
  unsigned short* w2p = (unsigned short*)(ws + off);
  off += 196608;
  unsigned short* w3p = (unsigned short*)(ws + off);
  off += 393216;
  unsigned short* wf1r = (unsigned short*)(ws + off);

  k_prep_w<<<1264, 256, 0, stream>>>(Wp, W1, W2, W3, wp1r, wp0r, w1p, w2p, w3p);
  k_prep_wf1<<<2000, 256, 16896, stream>>>(Wf1, wf1r);

  for (int c = 0; c < nchunk; ++c) {
    const float* xc = x + (size_t)c * chunkN * 8192;
    k_front<<<chunkN, 512, 64768, stream>>>(xc, wp0r, bp, wp1r, w1p, b1, w2p,
                                            b2, w3p, b3, h3c);
    k_fc1<<<(chunkN / 128) * 32, 512, 0, stream>>>(h3c, xc, wf1r, fpart, chunkN);
    k_fc1red<<<(chunkN * 400 + 255) / 256, 256, 0, stream>>>(fpart, bf1, fc,
                                                             chunkN);
    k_fc2<<<chunkN / 4, 256, 0, stream>>>(fc, Wf2, bf2, out + (size_t)c * chunkN);
  }
}

// Round 8
// 693.880 us; speedup vs baseline: 1.7685x; 1.1256x over previous
//
#include <hip/hip_runtime.h>

// ============================================================================
// CNN3_P r8 = r4-exact front + latency-pipelined fc1:
//  - front: r4's verified conv16 (full conv2/3, 94,976B LDS, MPW=MT/4, NPW=4)
//    + wp0r pre-transposed base weights + 5-way prep_wf1.
//  - fc1: double-buffered lB, T14 issue-early/write-late staging, one barrier
//    per K64 step, both-win A-prefetch. S=16 K-slices (1.96MB panels, 2/XCD).
//  - chunkN=2048 preferred (h3 127MB L3-resident), ladder adapts to ws_size.
// ============================================================================

typedef __attribute__((ext_vector_type(8))) short bf16x8;
typedef __attribute__((ext_vector_type(4))) float f32x4;
typedef __attribute__((ext_vector_type(8))) unsigned short u16x8;
typedef __attribute__((ext_vector_type(4))) unsigned short u16x4;

#define DEVINL __device__ __forceinline__

DEVINL unsigned short f2bf(float f) {
  unsigned u = __builtin_bit_cast(unsigned, f);
  return (unsigned short)((u + 0x7fffu + ((u >> 16) & 1u)) >> 16);  // RNE
}
DEVINL float bf2f(unsigned short h) {
  return __builtin_bit_cast(float, ((unsigned)h) << 16);
}
DEVINL f32x4 mfma16(bf16x8 a, bf16x8 b, f32x4 c) {
  return __builtin_amdgcn_mfma_f32_16x16x32_bf16(a, b, c, 0, 0, 0);
}
DEVINL float relu(float v) { return v > 0.f ? v : 0.f; }
// swizzled LDS index (u16 units): row r, col c, row-stride 2^sh u16
DEVINL int sxg(int r, int c, int sh) {
  return (r << sh) + (((c >> 3) ^ (r & 7)) << 3) + (c & 7);
}

constexpr int NB = 4096;

// ---------------------------------------------------------------- prep weights
// wp1r/wp0r: [p][i]/[i][p]. w1p/w2p/w3p per-fragment packed:
// frag f=(k*KS+ks)*MT+mt; lane l elem e: o=mt*16+(l&15), c=ks*32+(l>>4)*8+e
__global__ __launch_bounds__(256) void k_prep_w(
    const float* __restrict__ Wp, const float* __restrict__ W1,
    const float* __restrict__ W2, const float* __restrict__ W3,
    unsigned short* __restrict__ wp1r, unsigned short* __restrict__ wp0r,
    unsigned short* __restrict__ w1p, unsigned short* __restrict__ w2p,
    unsigned short* __restrict__ w3p) {
  int idx = blockIdx.x * 256 + threadIdx.x;
  if (idx < 4096) {
    int p = idx >> 6, i = idx & 63;
    wp1r[p * 64 + i] = f2bf(Wp[(p * 64 + i) * 2 + 1]);
    wp0r[i * 64 + p] = f2bf(Wp[(p * 64 + i) * 2 + 0]);
    return;
  }
  idx -= 4096;
  if (idx < 24576) {  // w1: KS=2, MT=8
    int f = idx >> 9, l = (idx >> 3) & 63, e = idx & 7;
    int mt = f & 7, t = f >> 3, ks = t & 1, k = t >> 1;
    int o = mt * 16 + (l & 15), c = ks * 32 + (l >> 4) * 8 + e;
    w1p[idx] = f2bf(W1[(o * 64 + c) * 3 + k]);
    return;
  }
  idx -= 24576;
  if (idx < 98304) {  // w2: KS=4, MT=16
    int f = idx >> 9, l = (idx >> 3) & 63, e = idx & 7;
    int mt = f & 15, t = f >> 4, ks = t & 3, k = t >> 2;
    int o = mt * 16 + (l & 15), c = ks * 32 + (l >> 4) * 8 + e;
    w2p[idx] = f2bf(W2[(o * 128 + c) * 3 + k]);
    return;
  }
  idx -= 98304;
  if (idx < 196608) {  // w3: KS=8, MT=16
    int f = idx >> 9, l = (idx >> 3) & 63, e = idx & 7;
    int mt = f & 15, t = f >> 4, ks = t & 7, k = t >> 3;
    int o = mt * 16 + (l & 15), c = ks * 32 + (l >> 4) * 8 + e;
    w3p[idx] = f2bf(W3[(o * 256 + c) * 3 + k]);
  }
}

// ---------------------------------------------------------------- Wf1 remap
// grid 400*5: m = bid/5, q = bid%5. q<4: h3-part o-range [q*64,(q+1)*64);
// q==4: x-part.
__global__ __launch_bounds__(256) void k_prep_wf1(const float* __restrict__ wf1,
                                                  unsigned short* __restrict__ wf1r) {
  extern __shared__ unsigned short tls[];  // 8448 u16
  const int m = blockIdx.x / 5, q = blockIdx.x % 5, tid = threadIdx.x;
  unsigned short* dst = wf1r + (size_t)m * 39168;
  if (q < 4) {
    const float* src = wf1 + (size_t)m * 39168 + q * 7744;
    for (int idx = tid; idx < 7744; idx += 256) {
      int o = idx / 121, l = idx - o * 121;
      tls[o * 132 + l] = f2bf(src[idx]);
    }
    __syncthreads();
    for (int idx = tid; idx < 7744; idx += 256) {
      int l = idx >> 6, o = idx & 63;
      dst[l * 256 + q * 64 + o] = tls[o * 132 + l];
    }
  } else {
    const float* src = wf1 + (size_t)m * 39168 + 30976;
    for (int idx = tid; idx < 8192; idx += 256) {
      int il = idx >> 7, cl = idx & 127;
      tls[cl * 66 + il] = f2bf(src[idx]);
    }
    __syncthreads();
    for (int idx = tid; idx < 8192; idx += 256) {
      int cl = idx >> 6, il = idx & 63;
      dst[30976 + idx] = tls[cl * 66 + il];
    }
  }
}

// ---------------------------------------------------------------- conv phase (r4)
// wave-grid 4m x 2n; wave = MPW m-tiles x 4 n-tiles. A coalesced from packed
// global (1KB/frag, L1/L2), B from swizzled LDS (each read feeds MPW MFMAs).
template <int CIN, int COUT, int LIN, int LOUT, int SSHI, int SSHO, bool TOGLB>
DEVINL void conv16(const unsigned short* in_lds,
                   const unsigned short* __restrict__ wpack,
                   const float* __restrict__ bias, unsigned short* out_lds,
                   unsigned short* h3, int b, int lane, int wv) {
  constexpr int KS = CIN / 32;
  constexpr int MT = COUT / 16;
  constexpr int MPW = MT / 4;
  const int lr = lane & 15, lq = lane >> 4;
  const int wm = wv >> 1, wn = wv & 1;
  f32x4 acc[MPW][4];
#pragma unroll
  for (int mi = 0; mi < MPW; ++mi)
#pragma unroll
    for (int ni = 0; ni < 4; ++ni) acc[mi][ni] = (f32x4){0.f, 0.f, 0.f, 0.f};
#pragma unroll
  for (int k = 0; k < 3; ++k)
#pragma unroll
    for (int ks = 0; ks < KS; ++ks) {
      bf16x8 a[MPW];
#pragma unroll
      for (int mi = 0; mi < MPW; ++mi)
        a[mi] = *(const bf16x8*)(wpack +
                                 (((k * KS + ks) * MT + wm * MPW + mi) << 9) +
                                 lane * 8);
      const int col = ks * 32 + lq * 8;
#pragma unroll
      for (int ni = 0; ni < 4; ++ni) {
        int l = (wn * 4 + ni) * 16 + lr + k;
        if (l > LIN - 1) l = LIN - 1;  // garbage cols >= LOUT, never stored
        bf16x8 bb = *(const bf16x8*)(in_lds + sxg(l, col, SSHI));
#pragma unroll
        for (int mi = 0; mi < MPW; ++mi)
          acc[mi][ni] = mfma16(a[mi], bb, acc[mi][ni]);
      }
    }
#pragma unroll
  for (int mi = 0; mi < MPW; ++mi) {
    const int o0 = (wm * MPW + mi) * 16 + lq * 4;
    const f32x4 bi = *(const f32x4*)(bias + o0);
#pragma unroll
    for (int ni = 0; ni < 4; ++ni) {
      const int l = (wn * 4 + ni) * 16 + lr;
      if (l < LOUT) {
        u16x4 pk;
#pragma unroll
        for (int r = 0; r < 4; ++r) pk[r] = f2bf(relu(acc[mi][ni][r] + bi[r]));
        if constexpr (TOGLB)
          *(u16x4*)(h3 + ((size_t)b * LOUT + l) * COUT + o0) = pk;
        else
          *(u16x4*)(out_lds + sxg(l, o0, SSHO)) = pk;
      }
    }
  }
}

// ---------------------------------------------------------------- fused front (r4)
// Regions (u16): A @0     : xs[128]<<6 -> h1s[125]<<7   (16000)
//                B @16000 : h0s[127]<<6 -> h2s[123]<<8  (31488)
// dyn LDS = 94,976 B.
__global__ __launch_bounds__(512) void k_front(
    const float* __restrict__ x, const unsigned short* __restrict__ wp0r,
    const float* __restrict__ bp, const unsigned short* __restrict__ wp1r,
    const unsigned short* __restrict__ w1p, const float* __restrict__ b1,
    const unsigned short* __restrict__ w2p, const float* __restrict__ b2,
    const unsigned short* __restrict__ w3p, const float* __restrict__ b3,
    unsigned short* __restrict__ h3) {
  extern __shared__ unsigned short lds[];
  unsigned short* xs = lds;
  unsigned short* h1s = lds;
  unsigned short* h0s = lds + 16000;
  unsigned short* h2s = lds + 16000;
  __shared__ float pbase[8][64];
  __shared__ float basel[64];
  const int b = blockIdx.x, tid = threadIdx.x;
  const int lane = tid & 63, wv = tid >> 6, lq = lane >> 4, lr = lane & 15;
  const float* xb = x + (size_t)b * 8192;

  // phase 0: stage x -> xs bf16 [cl][il] swizzled
  for (int idx = tid * 4; idx < 8192; idx += 2048) {
    f32x4 v = *(const f32x4*)(xb + idx);
    int c = idx >> 6, i = idx & 63;
    u16x4 pk;
#pragma unroll
    for (int r = 0; r < 4; ++r) pk[r] = f2bf(v[r]);
    *(u16x4*)(xs + sxg(c, i, 6)) = pk;
  }
  __syncthreads();

  // phase 0b: base[p] = sum_i Wp0[i][p]*x[b][i]  (xs row 0 unswizzled)
  {
    int p = tid & 63, q = tid >> 6;
    float s = 0.f;
#pragma unroll
    for (int t = 0; t < 8; ++t) {
      int i = q * 8 + t;
      s += bf2f(wp0r[i * 64 + p]) * bf2f(xs[i]);
    }
    pbase[q][p] = s;
  }
  __syncthreads();
  if (tid < 64) {
    float s = bp[tid];
#pragma unroll
    for (int q = 0; q < 8; ++q) s += pbase[q][tid];
    basel[tid] = s;
  }
  __syncthreads();

  // phase 1: pairwise GEMM -> h0s[127][64]
  {
    const int mt = wv & 3, nh = wv >> 2;
    f32x4 acc[4];
#pragma unroll
    for (int t = 0; t < 4; ++t) acc[t] = (f32x4){0.f, 0.f, 0.f, 0.f};
#pragma unroll
    for (int s = 0; s < 2; ++s) {
      bf16x8 a = *(const bf16x8*)(wp1r + (mt * 16 + lr) * 64 + s * 32 + lq * 8);
#pragma unroll
      for (int t = 0; t < 4; ++t) {
        int j = (nh * 4 + t) * 16 + lr;
        int row = j + 1 > 127 ? 127 : j + 1;
        bf16x8 bb = *(const bf16x8*)(xs + sxg(row, s * 32 + lq * 8, 6));
        acc[t] = mfma16(a, bb, acc[t]);
      }
    }
    const int m0 = mt * 16 + lq * 4;
    f32x4 bl;
#pragma unroll
    for (int r = 0; r < 4; ++r) bl[r] = basel[m0 + r];
#pragma unroll
    for (int t = 0; t < 4; ++t) {
      int j = (nh * 4 + t) * 16 + lr;
      if (j < 127) {
        u16x4 pk;
#pragma unroll
        for (int r = 0; r < 4; ++r) pk[r] = f2bf(relu(acc[t][r] + bl[r]));
        *(u16x4*)(h0s + sxg(j, m0, 6)) = pk;
      }
    }
  }
  __syncthreads();

  // conv1 64->128, 127->125
  conv16<64, 128, 127, 125, 6, 7, false>(h0s, w1p, b1, h1s, nullptr, b, lane, wv);
  __syncthreads();
  // conv2 128->256, 125->123
  conv16<128, 256, 125, 123, 7, 8, false>(h1s, w2p, b2, h2s, nullptr, b, lane, wv);
  __syncthreads();
  // conv3 256->256, 123->121 -> global h3 [b][l][o]
  conv16<256, 256, 123, 121, 8, 0, true>(h2s, w3p, b3, nullptr, h3, b, lane, wv);
}

// ---------------------------------------------------------------- fc1 (dbuf)
// Block 512 th, tile M=400 x N=128, K64 steps. Double-buffered lB + T14
// issue-early/write-late staging: one barrier per K64. A-frags (both wins)
// prefetch from L2 (slice panels 1.96MB, 2 per XCD at S=16).
__global__ __launch_bounds__(512) void k_fc1(const unsigned short* __restrict__ h3,
                                             const float* __restrict__ x,
                                             const unsigned short* __restrict__ wf1r,
                                             float* __restrict__ fpart,
                                             int chunkN, int S) {
  __shared__ unsigned short lB[2][128 * 64];
  const int tid = threadIdx.x;
  const int lane = tid & 63, wv = tid >> 6, lq = lane >> 4, lr = lane & 15;
  const int slice = blockIdx.x % S;
  const int bbase = (blockIdx.x / S) * 128;
  const int per = 612 / S, rem = 612 % S;
  const int c0 = slice * per + (slice < rem ? slice : rem);
  const int c1 = c0 + per + (slice < rem ? 1 : 0);

  f32x4 acc[3][8], acc24;
#pragma unroll
  for (int mi = 0; mi < 3; ++mi)
#pragma unroll
    for (int nt = 0; nt < 8; ++nt) acc[mi][nt] = (f32x4){0.f, 0.f, 0.f, 0.f};
  acc24 = (f32x4){0.f, 0.f, 0.f, 0.f};

  const size_t arow0 = (size_t)((3 * wv + 0) * 16 + lr) * 39168;
  const size_t arow1 = (size_t)((3 * wv + 1) * 16 + lr) * 39168;
  const size_t arow2 = (size_t)((3 * wv + 2) * 16 + lr) * 39168;
  const size_t arow24 = (size_t)(384 + lr) * 39168;

  // staging coords: thread stages 2 chunks (idx = tid + t*512 over 1024)
  const int sn0 = tid >> 3, sch0 = tid & 7;          // t=0
  const int sn1 = (tid + 512) >> 3, sch1 = tid & 7;  // t=1
  const unsigned short* hrow0 = h3 + (size_t)(bbase + sn0) * 30976 + sch0 * 8;
  const unsigned short* hrow1 = h3 + (size_t)(bbase + sn1) * 30976 + sch1 * 8;
  const float* xrow0 = x + (size_t)(bbase + sn0) * 8192 + sch0 * 8;
  const float* xrow1 = x + (size_t)(bbase + sn1) * 8192 + sch1 * 8;
  const int woff0 = (sn0 << 6) + ((sch0 ^ (sn0 & 7)) << 3);
  const int woff1 = (sn1 << 6) + ((sch1 ^ (sn1 & 7)) << 3);

  u16x8 hv0, hv1;
  f32x4 xv00, xv01, xv10, xv11;
  bool isx;

#define FC1_GLOAD(KC)                                                     \
  {                                                                       \
    const int k0_ = (KC)*64;                                              \
    isx = (k0_ >= 30976);                                                 \
    if (!isx) {                                                           \
      hv0 = *(const u16x8*)(hrow0 + k0_);                                 \
      hv1 = *(const u16x8*)(hrow1 + k0_);                                 \
    } else {                                                              \
      xv00 = *(const f32x4*)(xrow0 + (k0_ - 30976));                      \
      xv01 = *(const f32x4*)(xrow0 + (k0_ - 30976) + 4);                  \
      xv10 = *(const f32x4*)(xrow1 + (k0_ - 30976));                      \
      xv11 = *(const f32x4*)(xrow1 + (k0_ - 30976) + 4);                  \
    }                                                                     \
  }
#define FC1_DSWRITE(BUF)                                                  \
  {                                                                       \
    if (isx) {                                                            \
      _Pragma("unroll") for (int r = 0; r < 4; ++r) {                     \
        hv0[r] = f2bf(xv00[r]);                                           \
        hv0[4 + r] = f2bf(xv01[r]);                                       \
        hv1[r] = f2bf(xv10[r]);                                           \
        hv1[4 + r] = f2bf(xv11[r]);                                       \
      }                                                                   \
    }                                                                     \
    *(u16x8*)(lB[BUF] + woff0) = hv0;                                     \
    *(u16x8*)(lB[BUF] + woff1) = hv1;                                     \
  }

  FC1_GLOAD(c0)
  FC1_DSWRITE(0)
  __syncthreads();

  for (int kc = c0; kc < c1; ++kc) {
    const int p = (kc - c0) & 1;
    const int k0 = kc * 64;
    const bool more = (kc + 1 < c1);
    if (more) FC1_GLOAD(kc + 1)

    // prefetch A for both wins
    bf16x8 aP[2][4];
#pragma unroll
    for (int win = 0; win < 2; ++win) {
      const int koff = k0 + win * 32 + lq * 8;
      aP[win][0] = *(const bf16x8*)(wf1r + arow0 + koff);
      aP[win][1] = *(const bf16x8*)(wf1r + arow1 + koff);
      aP[win][2] = *(const bf16x8*)(wf1r + arow2 + koff);
      aP[win][3] = *(const bf16x8*)(wf1r + arow24 + koff);
    }
#pragma unroll
    for (int win = 0; win < 2; ++win) {
      const int cloc = win * 32 + lq * 8;
#pragma unroll
      for (int nt = 0; nt < 8; ++nt) {
        const int n = nt * 16 + lr;
        bf16x8 bb = *(const bf16x8*)(lB[p] + sxg(n, cloc, 6));
        acc[0][nt] = mfma16(aP[win][0], bb, acc[0][nt]);
        acc[1][nt] = mfma16(aP[win][1], bb, acc[1][nt]);
        acc[2][nt] = mfma16(aP[win][2], bb, acc[2][nt]);
      }
      {
        const int n = wv * 16 + lr;
        bf16x8 bb = *(const bf16x8*)(lB[p] + sxg(n, cloc, 6));
        acc24 = mfma16(aP[win][3], bb, acc24);
      }
    }
    if (more) FC1_DSWRITE(p ^ 1)
    __syncthreads();
  }
#undef FC1_GLOAD
#undef FC1_DSWRITE

#pragma unroll
  for (int mi = 0; mi < 3; ++mi) {
    const int m0 = (3 * wv + mi) * 16 + lq * 4;
#pragma unroll
    for (int nt = 0; nt < 8; ++nt) {
      const int bb = bbase + nt * 16 + lr;
      *(f32x4*)(fpart + ((size_t)slice * chunkN + bb) * 400 + m0) = acc[mi][nt];
    }
  }
  {
    const int bb = bbase + wv * 16 + lr;
    *(f32x4*)(fpart + ((size_t)slice * chunkN + bb) * 400 + 384 + lq * 4) = acc24;
  }
}

__global__ __launch_bounds__(256) void k_fc1red(const float* __restrict__ fpart,
                                                const float* __restrict__ bf1,
                                                float* __restrict__ fc,
                                                int chunkN, int S) {
  int idx = blockIdx.x * 256 + threadIdx.x;
  if (idx >= chunkN * 400) return;
  int m = idx % 400;
  float s = bf1[m];
  size_t stride = (size_t)chunkN * 400;
#pragma unroll 4
  for (int sl = 0; sl < S; ++sl) s += fpart[(size_t)sl * stride + idx];
  fc[idx] = relu(s);
}

__global__ __launch_bounds__(256) void k_fc2(const float* __restrict__ fc,
                                             const float* __restrict__ wf2,
                                             const float* __restrict__ bf2,
                                             float* __restrict__ out) {
  int b = blockIdx.x * 4 + (threadIdx.x >> 6);
  int lane = threadIdx.x & 63;
  float s = 0.f;
  for (int m = lane; m < 400; m += 64) s += fc[(size_t)b * 400 + m] * wf2[m];
#pragma unroll
  for (int off = 32; off > 0; off >>= 1) s += __shfl_down(s, off, 64);
  if (lane == 0) out[b] = s + bf2[0];
}

// ---------------------------------------------------------------- launch
extern "C" void kernel_launch(void* const* d_in, const int* in_sizes, int n_in,
                              void* d_out, int out_size, void* d_ws, size_t ws_size,
                              hipStream_t stream) {
  const float* x = (const float*)d_in[0];
  const float* Wp = (const float*)d_in[1];
  const float* bp = (const float*)d_in[2];
  const float* W1 = (const float*)d_in[3];
  const float* b1 = (const float*)d_in[4];
  const float* W2 = (const float*)d_in[5];
  const float* b2 = (const float*)d_in[6];
  const float* W3 = (const float*)d_in[7];
  const float* b3 = (const float*)d_in[8];
  const float* Wf1 = (const float*)d_in[9];
  const float* bf1 = (const float*)d_in[10];
  const float* Wf2 = (const float*)d_in[11];
  const float* bf2 = (const float*)d_in[12];
  float* out = (float*)d_out;

  const size_t fixed =
      8192 + 8192 + 49152 + 196608 + 393216 + 400ULL * 39168 * 2;
  const int S = 16;
  static const int cand[3] = {2048, 1024, 512};
  int chunkN = 512;
  for (int i = 0; i < 3; ++i) {
    size_t cn = cand[i];
    size_t need = fixed + cn * 61952ULL + (size_t)S * cn * 1600ULL + cn * 1600ULL;
    if (need <= ws_size) {
      chunkN = cand[i];
      break;
    }
  }
  const int nchunk = NB / chunkN;

  char* ws = (char*)d_ws;
  size_t off = 0;
  unsigned short* h3c = (unsigned short*)(ws + off);
  off += (size_t)chunkN * 61952ULL;
  float* fpart = (float*)(ws + off);
  off += (size_t)S * chunkN * 1600ULL;
  float* fc = (float*)(ws + off);
  off += (size_t)chunkN * 1600ULL;
  unsigned short* wp1r = (unsigned short*)(ws + off);
  off += 8192;
  unsigned short* wp0r = (unsigned short*)(ws + off);
  off += 8192;
  unsigned short* w1p = (unsigned short*)(ws + off);
  off += 49152;
  unsigned short* w2p = (unsigned short*)(ws + off);
  off += 196608;
  unsigned short* w3p = (unsigned short*)(ws + off);
  off += 393216;
  unsigned short* wf1r = (unsigned short*)(ws + off);

  k_prep_w<<<1264, 256, 0, stream>>>(Wp, W1, W2, W3, wp1r, wp0r, w1p, w2p, w3p);
  k_prep_wf1<<<2000, 256, 16896, stream>>>(Wf1, wf1r);

  for (int c = 0; c < nchunk; ++c) {
    const float* xc = x + (size_t)c * chunkN * 8192;
    k_front<<<chunkN, 512, 94976, stream>>>(xc, wp0r, bp, wp1r, w1p, b1, w2p,
                                            b2, w3p, b3, h3c);
    k_fc1<<<(chunkN / 128) * S, 512, 0, stream>>>(h3c, xc, wf1r, fpart, chunkN, S);
    k_fc1red<<<(chunkN * 400 + 255) / 256, 256, 0, stream>>>(fpart, bf1, fc,
                                                             chunkN, S);
    k_fc2<<<chunkN / 4, 256, 0, stream>>>(fc, Wf2, bf2, out + (size_t)c * chunkN);
  }
}

// Round 9
// 686.060 us; speedup vs baseline: 1.7887x; 1.0114x over previous
//
#include <hip/hip_runtime.h>

// ============================================================================
// CNN3_P r9 = r8 + ILP unlock:
//  - k_front/k_fc1: __launch_bounds__(512,1) -> VGPR budget 256 (LDS/grid
//    already force 1 block/CU; r8's 92-VGPR allocation left the latency-hiding
//    registers on the table).
//  - fc1: explicit A-fragment double-buffer (next iter's wf1r loads issued
//    before current MFMAs), #pragma unroll 2 on the K-loop.
// ============================================================================

typedef __attribute__((ext_vector_type(8))) short bf16x8;
typedef __attribute__((ext_vector_type(4))) float f32x4;
typedef __attribute__((ext_vector_type(8))) unsigned short u16x8;
typedef __attribute__((ext_vector_type(4))) unsigned short u16x4;

#define DEVINL __device__ __forceinline__

DEVINL unsigned short f2bf(float f) {
  unsigned u = __builtin_bit_cast(unsigned, f);
  return (unsigned short)((u + 0x7fffu + ((u >> 16) & 1u)) >> 16);  // RNE
}
DEVINL float bf2f(unsigned short h) {
  return __builtin_bit_cast(float, ((unsigned)h) << 16);
}
DEVINL f32x4 mfma16(bf16x8 a, bf16x8 b, f32x4 c) {
  return __builtin_amdgcn_mfma_f32_16x16x32_bf16(a, b, c, 0, 0, 0);
}
DEVINL float relu(float v) { return v > 0.f ? v : 0.f; }
// swizzled LDS index (u16 units): row r, col c, row-stride 2^sh u16
DEVINL int sxg(int r, int c, int sh) {
  return (r << sh) + (((c >> 3) ^ (r & 7)) << 3) + (c & 7);
}

constexpr int NB = 4096;

// ---------------------------------------------------------------- prep weights
// wp1r/wp0r: [p][i]/[i][p]. w1p/w2p/w3p per-fragment packed:
// frag f=(k*KS+ks)*MT+mt; lane l elem e: o=mt*16+(l&15), c=ks*32+(l>>4)*8+e
__global__ __launch_bounds__(256) void k_prep_w(
    const float* __restrict__ Wp, const float* __restrict__ W1,
    const float* __restrict__ W2, const float* __restrict__ W3,
    unsigned short* __restrict__ wp1r, unsigned short* __restrict__ wp0r,
    unsigned short* __restrict__ w1p, unsigned short* __restrict__ w2p,
    unsigned short* __restrict__ w3p) {
  int idx = blockIdx.x * 256 + threadIdx.x;
  if (idx < 4096) {
    int p = idx >> 6, i = idx & 63;
    wp1r[p * 64 + i] = f2bf(Wp[(p * 64 + i) * 2 + 1]);
    wp0r[i * 64 + p] = f2bf(Wp[(p * 64 + i) * 2 + 0]);
    return;
  }
  idx -= 4096;
  if (idx < 24576) {  // w1: KS=2, MT=8
    int f = idx >> 9, l = (idx >> 3) & 63, e = idx & 7;
    int mt = f & 7, t = f >> 3, ks = t & 1, k = t >> 1;
    int o = mt * 16 + (l & 15), c = ks * 32 + (l >> 4) * 8 + e;
    w1p[idx] = f2bf(W1[(o * 64 + c) * 3 + k]);
    return;
  }
  idx -= 24576;
  if (idx < 98304) {  // w2: KS=4, MT=16
    int f = idx >> 9, l = (idx >> 3) & 63, e = idx & 7;
    int mt = f & 15, t = f >> 4, ks = t & 3, k = t >> 2;
    int o = mt * 16 + (l & 15), c = ks * 32 + (l >> 4) * 8 + e;
    w2p[idx] = f2bf(W2[(o * 128 + c) * 3 + k]);
    return;
  }
  idx -= 98304;
  if (idx < 196608) {  // w3: KS=8, MT=16
    int f = idx >> 9, l = (idx >> 3) & 63, e = idx & 7;
    int mt = f & 15, t = f >> 4, ks = t & 7, k = t >> 3;
    int o = mt * 16 + (l & 15), c = ks * 32 + (l >> 4) * 8 + e;
    w3p[idx] = f2bf(W3[(o * 256 + c) * 3 + k]);
  }
}

// ---------------------------------------------------------------- Wf1 remap
// grid 400*5: m = bid/5, q = bid%5. q<4: h3-part o-range [q*64,(q+1)*64);
// q==4: x-part.
__global__ __launch_bounds__(256) void k_prep_wf1(const float* __restrict__ wf1,
                                                  unsigned short* __restrict__ wf1r) {
  extern __shared__ unsigned short tls[];  // 8448 u16
  const int m = blockIdx.x / 5, q = blockIdx.x % 5, tid = threadIdx.x;
  unsigned short* dst = wf1r + (size_t)m * 39168;
  if (q < 4) {
    const float* src = wf1 + (size_t)m * 39168 + q * 7744;
    for (int idx = tid; idx < 7744; idx += 256) {
      int o = idx / 121, l = idx - o * 121;
      tls[o * 132 + l] = f2bf(src[idx]);
    }
    __syncthreads();
    for (int idx = tid; idx < 7744; idx += 256) {
      int l = idx >> 6, o = idx & 63;
      dst[l * 256 + q * 64 + o] = tls[o * 132 + l];
    }
  } else {
    const float* src = wf1 + (size_t)m * 39168 + 30976;
    for (int idx = tid; idx < 8192; idx += 256) {
      int il = idx >> 7, cl = idx & 127;
      tls[cl * 66 + il] = f2bf(src[idx]);
    }
    __syncthreads();
    for (int idx = tid; idx < 8192; idx += 256) {
      int cl = idx >> 6, il = idx & 63;
      dst[30976 + idx] = tls[cl * 66 + il];
    }
  }
}

// ---------------------------------------------------------------- conv phase (r4)
// wave-grid 4m x 2n; wave = MPW m-tiles x 4 n-tiles. A coalesced from packed
// global (1KB/frag, L1/L2), B from swizzled LDS (each read feeds MPW MFMAs).
template <int CIN, int COUT, int LIN, int LOUT, int SSHI, int SSHO, bool TOGLB>
DEVINL void conv16(const unsigned short* in_lds,
                   const unsigned short* __restrict__ wpack,
                   const float* __restrict__ bias, unsigned short* out_lds,
                   unsigned short* h3, int b, int lane, int wv) {
  constexpr int KS = CIN / 32;
  constexpr int MT = COUT / 16;
  constexpr int MPW = MT / 4;
  const int lr = lane & 15, lq = lane >> 4;
  const int wm = wv >> 1, wn = wv & 1;
  f32x4 acc[MPW][4];
#pragma unroll
  for (int mi = 0; mi < MPW; ++mi)
#pragma unroll
    for (int ni = 0; ni < 4; ++ni) acc[mi][ni] = (f32x4){0.f, 0.f, 0.f, 0.f};
#pragma unroll
  for (int k = 0; k < 3; ++k)
#pragma unroll
    for (int ks = 0; ks < KS; ++ks) {
      bf16x8 a[MPW];
#pragma unroll
      for (int mi = 0; mi < MPW; ++mi)
        a[mi] = *(const bf16x8*)(wpack +
                                 (((k * KS + ks) * MT + wm * MPW + mi) << 9) +
                                 lane * 8);
      const int col = ks * 32 + lq * 8;
#pragma unroll
      for (int ni = 0; ni < 4; ++ni) {
        int l = (wn * 4 + ni) * 16 + lr + k;
        if (l > LIN - 1) l = LIN - 1;  // garbage cols >= LOUT, never stored
        bf16x8 bb = *(const bf16x8*)(in_lds + sxg(l, col, SSHI));
#pragma unroll
        for (int mi = 0; mi < MPW; ++mi)
          acc[mi][ni] = mfma16(a[mi], bb, acc[mi][ni]);
      }
    }
#pragma unroll
  for (int mi = 0; mi < MPW; ++mi) {
    const int o0 = (wm * MPW + mi) * 16 + lq * 4;
    const f32x4 bi = *(const f32x4*)(bias + o0);
#pragma unroll
    for (int ni = 0; ni < 4; ++ni) {
      const int l = (wn * 4 + ni) * 16 + lr;
      if (l < LOUT) {
        u16x4 pk;
#pragma unroll
        for (int r = 0; r < 4; ++r) pk[r] = f2bf(relu(acc[mi][ni][r] + bi[r]));
        if constexpr (TOGLB)
          *(u16x4*)(h3 + ((size_t)b * LOUT + l) * COUT + o0) = pk;
        else
          *(u16x4*)(out_lds + sxg(l, o0, SSHO)) = pk;
      }
    }
  }
}

// ---------------------------------------------------------------- fused front (r4)
// Regions (u16): A @0     : xs[128]<<6 -> h1s[125]<<7   (16000)
//                B @16000 : h0s[127]<<6 -> h2s[123]<<8  (31488)
// dyn LDS = 94,976 B -> 1 block/CU regardless, so (512,1) frees VGPRs for ILP.
__global__ __launch_bounds__(512, 1) void k_front(
    const float* __restrict__ x, const unsigned short* __restrict__ wp0r,
    const float* __restrict__ bp, const unsigned short* __restrict__ wp1r,
    const unsigned short* __restrict__ w1p, const float* __restrict__ b1,
    const unsigned short* __restrict__ w2p, const float* __restrict__ b2,
    const unsigned short* __restrict__ w3p, const float* __restrict__ b3,
    unsigned short* __restrict__ h3) {
  extern __shared__ unsigned short lds[];
  unsigned short* xs = lds;
  unsigned short* h1s = lds;
  unsigned short* h0s = lds + 16000;
  unsigned short* h2s = lds + 16000;
  __shared__ float pbase[8][64];
  __shared__ float basel[64];
  const int b = blockIdx.x, tid = threadIdx.x;
  const int lane = tid & 63, wv = tid >> 6, lq = lane >> 4, lr = lane & 15;
  const float* xb = x + (size_t)b * 8192;

  // phase 0: stage x -> xs bf16 [cl][il] swizzled
  for (int idx = tid * 4; idx < 8192; idx += 2048) {
    f32x4 v = *(const f32x4*)(xb + idx);
    int c = idx >> 6, i = idx & 63;
    u16x4 pk;
#pragma unroll
    for (int r = 0; r < 4; ++r) pk[r] = f2bf(v[r]);
    *(u16x4*)(xs + sxg(c, i, 6)) = pk;
  }
  __syncthreads();

  // phase 0b: base[p] = sum_i Wp0[i][p]*x[b][i]  (xs row 0 unswizzled)
  {
    int p = tid & 63, q = tid >> 6;
    float s = 0.f;
#pragma unroll
    for (int t = 0; t < 8; ++t) {
      int i = q * 8 + t;
      s += bf2f(wp0r[i * 64 + p]) * bf2f(xs[i]);
    }
    pbase[q][p] = s;
  }
  __syncthreads();
  if (tid < 64) {
    float s = bp[tid];
#pragma unroll
    for (int q = 0; q < 8; ++q) s += pbase[q][tid];
    basel[tid] = s;
  }
  __syncthreads();

  // phase 1: pairwise GEMM -> h0s[127][64]
  {
    const int mt = wv & 3, nh = wv >> 2;
    f32x4 acc[4];
#pragma unroll
    for (int t = 0; t < 4; ++t) acc[t] = (f32x4){0.f, 0.f, 0.f, 0.f};
#pragma unroll
    for (int s = 0; s < 2; ++s) {
      bf16x8 a = *(const bf16x8*)(wp1r + (mt * 16 + lr) * 64 + s * 32 + lq * 8);
#pragma unroll
      for (int t = 0; t < 4; ++t) {
        int j = (nh * 4 + t) * 16 + lr;
        int row = j + 1 > 127 ? 127 : j + 1;
        bf16x8 bb = *(const bf16x8*)(xs + sxg(row, s * 32 + lq * 8, 6));
        acc[t] = mfma16(a, bb, acc[t]);
      }
    }
    const int m0 = mt * 16 + lq * 4;
    f32x4 bl;
#pragma unroll
    for (int r = 0; r < 4; ++r) bl[r] = basel[m0 + r];
#pragma unroll
    for (int t = 0; t < 4; ++t) {
      int j = (nh * 4 + t) * 16 + lr;
      if (j < 127) {
        u16x4 pk;
#pragma unroll
        for (int r = 0; r < 4; ++r) pk[r] = f2bf(relu(acc[t][r] + bl[r]));
        *(u16x4*)(h0s + sxg(j, m0, 6)) = pk;
      }
    }
  }
  __syncthreads();

  // conv1 64->128, 127->125
  conv16<64, 128, 127, 125, 6, 7, false>(h0s, w1p, b1, h1s, nullptr, b, lane, wv);
  __syncthreads();
  // conv2 128->256, 125->123
  conv16<128, 256, 125, 123, 7, 8, false>(h1s, w2p, b2, h2s, nullptr, b, lane, wv);
  __syncthreads();
  // conv3 256->256, 123->121 -> global h3 [b][l][o]
  conv16<256, 256, 123, 121, 8, 0, true>(h2s, w3p, b3, nullptr, h3, b, lane, wv);
}

// ---------------------------------------------------------------- fc1 (dbuf+Apf)
// Block 512 th, tile M=400 x N=128, K64 steps. Double-buffered lB (T14
// issue-early/write-late), A-fragment double-buffer (next iter's wf1r loads
// before current MFMAs), one barrier per K64. S=16 slices (1.96MB panels).
// grid = 256 = 1 block/CU -> (512,1) for full VGPR budget (ILP-hiding).
__global__ __launch_bounds__(512, 1) void k_fc1(
    const unsigned short* __restrict__ h3, const float* __restrict__ x,
    const unsigned short* __restrict__ wf1r, float* __restrict__ fpart,
    int chunkN, int S) {
  __shared__ unsigned short lB[2][128 * 64];
  const int tid = threadIdx.x;
  const int lane = tid & 63, wv = tid >> 6, lq = lane >> 4, lr = lane & 15;
  const int slice = blockIdx.x % S;
  const int bbase = (blockIdx.x / S) * 128;
  const int per = 612 / S, rem = 612 % S;
  const int c0 = slice * per + (slice < rem ? slice : rem);
  const int c1 = c0 + per + (slice < rem ? 1 : 0);

  f32x4 acc[3][8], acc24;
#pragma unroll
  for (int mi = 0; mi < 3; ++mi)
#pragma unroll
    for (int nt = 0; nt < 8; ++nt) acc[mi][nt] = (f32x4){0.f, 0.f, 0.f, 0.f};
  acc24 = (f32x4){0.f, 0.f, 0.f, 0.f};

  const size_t arow0 = (size_t)((3 * wv + 0) * 16 + lr) * 39168;
  const size_t arow1 = (size_t)((3 * wv + 1) * 16 + lr) * 39168;
  const size_t arow2 = (size_t)((3 * wv + 2) * 16 + lr) * 39168;
  const size_t arow24 = (size_t)(384 + lr) * 39168;

  // staging coords: thread stages 2 chunks (idx = tid + t*512 over 1024)
  const int sn0 = tid >> 3, sch0 = tid & 7;          // t=0
  const int sn1 = (tid + 512) >> 3, sch1 = tid & 7;  // t=1
  const unsigned short* hrow0 = h3 + (size_t)(bbase + sn0) * 30976 + sch0 * 8;
  const unsigned short* hrow1 = h3 + (size_t)(bbase + sn1) * 30976 + sch1 * 8;
  const float* xrow0 = x + (size_t)(bbase + sn0) * 8192 + sch0 * 8;
  const float* xrow1 = x + (size_t)(bbase + sn1) * 8192 + sch1 * 8;
  const int woff0 = (sn0 << 6) + ((sch0 ^ (sn0 & 7)) << 3);
  const int woff1 = (sn1 << 6) + ((sch1 ^ (sn1 & 7)) << 3);

  u16x8 hv0, hv1;
  f32x4 xv00, xv01, xv10, xv11;
  bool isx;

#define FC1_GLOAD(KC)                                                     \
  {                                                                       \
    const int k0_ = (KC)*64;                                              \
    isx = (k0_ >= 30976);                                                 \
    if (!isx) {                                                           \
      hv0 = *(const u16x8*)(hrow0 + k0_);                                 \
      hv1 = *(const u16x8*)(hrow1 + k0_);                                 \
    } else {                                                              \
      xv00 = *(const f32x4*)(xrow0 + (k0_ - 30976));                      \
      xv01 = *(const f32x4*)(xrow0 + (k0_ - 30976) + 4);                  \
      xv10 = *(const f32x4*)(xrow1 + (k0_ - 30976));                      \
      xv11 = *(const f32x4*)(xrow1 + (k0_ - 30976) + 4);                  \
    }                                                                     \
  }
#define FC1_DSWRITE(BUF)                                                  \
  {                                                                       \
    if (isx) {                                                            \
      _Pragma("unroll") for (int r = 0; r < 4; ++r) {                     \
        hv0[r] = f2bf(xv00[r]);                                           \
        hv0[4 + r] = f2bf(xv01[r]);                                       \
        hv1[r] = f2bf(xv10[r]);                                           \
        hv1[4 + r] = f2bf(xv11[r]);                                       \
      }                                                                   \
    }                                                                     \
    *(u16x8*)(lB[BUF] + woff0) = hv0;                                     \
    *(u16x8*)(lB[BUF] + woff1) = hv1;                                     \
  }
#define FC1_ALOAD(DST, KC)                                                \
  {                                                                       \
    const int ka_ = (KC)*64;                                              \
    _Pragma("unroll") for (int win = 0; win < 2; ++win) {                 \
      const int koff = ka_ + win * 32 + lq * 8;                           \
      DST[win][0] = *(const bf16x8*)(wf1r + arow0 + koff);                \
      DST[win][1] = *(const bf16x8*)(wf1r + arow1 + koff);                \
      DST[win][2] = *(const bf16x8*)(wf1r + arow2 + koff);                \
      DST[win][3] = *(const bf16x8*)(wf1r + arow24 + koff);               \
    }                                                                     \
  }

  bf16x8 aC[2][4], aN[2][4];
  FC1_GLOAD(c0)
  FC1_DSWRITE(0)
  FC1_ALOAD(aC, c0)
  __syncthreads();

#pragma unroll 2
  for (int kc = c0; kc < c1; ++kc) {
    const int p = (kc - c0) & 1;
    const bool more = (kc + 1 < c1);
    if (more) {
      FC1_GLOAD(kc + 1)
      FC1_ALOAD(aN, kc + 1)
    }
#pragma unroll
    for (int win = 0; win < 2; ++win) {
      const int cloc = win * 32 + lq * 8;
#pragma unroll
      for (int nt = 0; nt < 8; ++nt) {
        const int n = nt * 16 + lr;
        bf16x8 bb = *(const bf16x8*)(lB[p] + sxg(n, cloc, 6));
        acc[0][nt] = mfma16(aC[win][0], bb, acc[0][nt]);
        acc[1][nt] = mfma16(aC[win][1], bb, acc[1][nt]);
        acc[2][nt] = mfma16(aC[win][2], bb, acc[2][nt]);
      }
      {
        const int n = wv * 16 + lr;
        bf16x8 bb = *(const bf16x8*)(lB[p] + sxg(n, cloc, 6));
        acc24 = mfma16(aC[win][3], bb, acc24);
      }
    }
    if (more) FC1_DSWRITE(p ^ 1)
    __syncthreads();
#pragma unroll
    for (int w2 = 0; w2 < 2; ++w2)
#pragma unroll
      for (int i = 0; i < 4; ++i) aC[w2][i] = aN[w2][i];
  }
#undef FC1_GLOAD
#undef FC1_DSWRITE
#undef FC1_ALOAD

#pragma unroll
  for (int mi = 0; mi < 3; ++mi) {
    const int m0 = (3 * wv + mi) * 16 + lq * 4;
#pragma unroll
    for (int nt = 0; nt < 8; ++nt) {
      const int bb = bbase + nt * 16 + lr;
      *(f32x4*)(fpart + ((size_t)slice * chunkN + bb) * 400 + m0) = acc[mi][nt];
    }
  }
  {
    const int bb = bbase + wv * 16 + lr;
    *(f32x4*)(fpart + ((size_t)slice * chunkN + bb) * 400 + 384 + lq * 4) = acc24;
  }
}

__global__ __launch_bounds__(256) void k_fc1red(const float* __restrict__ fpart,
                                                const float* __restrict__ bf1,
                                                float* __restrict__ fc,
                                                int chunkN, int S) {
  int idx = blockIdx.x * 256 + threadIdx.x;
  if (idx >= chunkN * 400) return;
  int m = idx % 400;
  float s = bf1[m];
  size_t stride = (size_t)chunkN * 400;
#pragma unroll 4
  for (int sl = 0; sl < S; ++sl) s += fpart[(size_t)sl * stride + idx];
  fc[idx] = relu(s);
}

__global__ __launch_bounds__(256) void k_fc2(const float* __restrict__ fc,
                                             const float* __restrict__ wf2,
                                             const float* __restrict__ bf2,
                                             float* __restrict__ out) {
  int b = blockIdx.x * 4 + (threadIdx.x >> 6);
  int lane = threadIdx.x & 63;
  float s = 0.f;
  for (int m = lane; m < 400; m += 64) s += fc[(size_t)b * 400 + m] * wf2[m];
#pragma unroll
  for (int off = 32; off > 0; off >>= 1) s += __shfl_down(s, off, 64);
  if (lane == 0) out[b] = s + bf2[0];
}

// ---------------------------------------------------------------- launch
extern "C" void kernel_launch(void* const* d_in, const int* in_sizes, int n_in,
                              void* d_out, int out_size, void* d_ws, size_t ws_size,
                              hipStream_t stream) {
  const float* x = (const float*)d_in[0];
  const float* Wp = (const float*)d_in[1];
  const float* bp = (const float*)d_in[2];
  const float* W1 = (const float*)d_in[3];
  const float* b1 = (const float*)d_in[4];
  const float* W2 = (const float*)d_in[5];
  const float* b2 = (const float*)d_in[6];
  const float* W3 = (const float*)d_in[7];
  const float* b3 = (const float*)d_in[8];
  const float* Wf1 = (const float*)d_in[9];
  const float* bf1 = (const float*)d_in[10];
  const float* Wf2 = (const float*)d_in[11];
  const float* bf2 = (const float*)d_in[12];
  float* out = (float*)d_out;

  const size_t fixed =
      8192 + 8192 + 49152 + 196608 + 393216 + 400ULL * 39168 * 2;
  const int S = 16;
  static const int cand[3] = {2048, 1024, 512};
  int chunkN = 512;
  for (int i = 0; i < 3; ++i) {
    size_t cn = cand[i];
    size_t need = fixed + cn * 61952ULL + (size_t)S * cn * 1600ULL + cn * 1600ULL;
    if (need <= ws_size) {
      chunkN = cand[i];
      break;
    }
  }
  const int nchunk = NB / chunkN;

  char* ws = (char*)d_ws;
  size_t off = 0;
  unsigned short* h3c = (unsigned short*)(ws + off);
  off += (size_t)chunkN * 61952ULL;
  float* fpart = (float*)(ws + off);
  off += (size_t)S * chunkN * 1600ULL;
  float* fc = (float*)(ws + off);
  off += (size_t)chunkN * 1600ULL;
  unsigned short* wp1r = (unsigned short*)(ws + off);
  off += 8192;
  unsigned short* wp0r = (unsigned short*)(ws + off);
  off += 8192;
  unsigned short* w1p = (unsigned short*)(ws + off);
  off += 49152;
  unsigned short* w2p = (unsigned short*)(ws + off);
  off += 196608;
  unsigned short* w3p = (unsigned short*)(ws + off);
  off += 393216;
  unsigned short* wf1r = (unsigned short*)(ws + off);

  k_prep_w<<<1264, 256, 0, stream>>>(Wp, W1, W2, W3, wp1r, wp0r, w1p, w2p, w3p);
  k_prep_wf1<<<2000, 256, 16896, stream>>>(Wf1, wf1r);

  for (int c = 0; c < nchunk; ++c) {
    const float* xc = x + (size_t)c * chunkN * 8192;
    k_front<<<chunkN, 512, 94976, stream>>>(xc, wp0r, bp, wp1r, w1p, b1, w2p,
                                            b2, w3p, b3, h3c);
    k_fc1<<<(chunkN / 128) * S, 512, 0, stream>>>(h3c, xc, wf1r, fpart, chunkN, S);
    k_fc1red<<<(chunkN * 400 + 255) / 256, 256, 0, stream>>>(fpart, bf1, fc,
                                                             chunkN, S);
    k_fc2<<<chunkN / 4, 256, 0, stream>>>(fc, Wf2, bf2, out + (size_t)c * chunkN);
  }
}